// Round 2
// baseline (524.666 us; speedup 1.0000x reference)
//
#include <hip/hip_runtime.h>

// dx[n,l,o] = weight[o,l]  — broadcast transpose of weight (OUT x L) into (N, L, OUT).
// N=128, L=1024, OUT=1024. Output 512 MiB f32: pure HBM-write-bound.

typedef float f32x4 __attribute__((ext_vector_type(4)));  // native vector: OK for nontemporal builtin

constexpr int TL = 64;          // tile extent in l
constexpr int TO = 64;          // tile extent in o
constexpr int LDS_STRIDE = 68;  // 68*4 = 272 B row pitch: 16B-aligned float4 reads, spread banks
constexpr int NCHUNK = 16;      // n-slices written per block

__global__ __launch_bounds__(256) void bcast_transpose_kernel(
    const float* __restrict__ w, float* __restrict__ out,
    int L, int OUT, long long slice_elems /* L*OUT */) {
  __shared__ float tile[TL * LDS_STRIDE];

  const int t = threadIdx.x;
  const int c  = t & 15;   // float4 column index within a 64-float row (16 per row)
  const int r0 = t >> 4;   // 0..15: base row within tile

  const int o_base = blockIdx.x * TO;
  const int l_base = blockIdx.y * TL;
  const int n_base = blockIdx.z * NCHUNK;

  // ---- Load weight tile (coalesced: contiguous l within a row of weight) and
  //      transpose into LDS: tile[l][o] = weight[o_base+o][l_base+l].
  for (int it = 0; it < 4; ++it) {
    const int o = r0 + it * 16;  // row within tile (o-dimension)
    const f32x4 v = *reinterpret_cast<const f32x4*>(
        w + (size_t)(o_base + o) * L + l_base + c * 4);
    const int l = c * 4;
    tile[(l + 0) * LDS_STRIDE + o] = v.x;
    tile[(l + 1) * LDS_STRIDE + o] = v.y;
    tile[(l + 2) * LDS_STRIDE + o] = v.z;
    tile[(l + 3) * LDS_STRIDE + o] = v.w;
  }
  __syncthreads();

  // ---- Pull this thread's 4 output float4s (16 floats) into registers once.
  f32x4 vals[4];
#pragma unroll
  for (int it = 0; it < 4; ++it) {
    const int l = r0 + it * 16;
    vals[it] = *reinterpret_cast<const f32x4*>(&tile[l * LDS_STRIDE + c * 4]);
  }

  // ---- Broadcast-write to NCHUNK n-slices. Coalesced float4 nontemporal stores
  //      (output is write-once-never-read; skip cache fill).
#pragma unroll 1
  for (int ni = 0; ni < NCHUNK; ++ni) {
    float* outn = out + (size_t)(n_base + ni) * slice_elems;
#pragma unroll
    for (int it = 0; it < 4; ++it) {
      const int l = r0 + it * 16;
      f32x4* dst = reinterpret_cast<f32x4*>(
          outn + (size_t)(l_base + l) * OUT + o_base + c * 4);
      __builtin_nontemporal_store(vals[it], dst);
    }
  }
}

extern "C" void kernel_launch(void* const* d_in, const int* in_sizes, int n_in,
                              void* d_out, int out_size, void* d_ws, size_t ws_size,
                              hipStream_t stream) {
  const float* w = (const float*)d_in[1];   // weight: (OUT, L)
  float* out = (float*)d_out;               // (N, L, OUT)

  const int L = 1024;
  const int N = in_sizes[0] / L;            // 128
  const int OUT = in_sizes[1] / L;          // 1024
  const long long slice = (long long)L * OUT;

  dim3 grid(OUT / TO, L / TL, N / NCHUNK);  // (16, 16, 8) = 2048 blocks
  dim3 block(256);
  bcast_transpose_kernel<<<grid, block, 0, stream>>>(w, out, L, OUT, slice);
}